// Round 2
// baseline (425.894 us; speedup 1.0000x reference)
//
#include <hip/hip_runtime.h>
#include <hip/hip_bf16.h>
#include <stdint.h>

#define D_IN  4096
#define D_OUT 4096
#define MROWS 8192   // 2 * 4096 rows of x

using i32x4 = __attribute__((ext_vector_type(4))) int;

// -------- Kernel 1 (fused): RMSNorm -> i8 xn (per-row absmax scale)
//          AND w_q fp32 -> i8 (exact, values in {-1,0,1}) ------------------
__global__ __launch_bounds__(256) void prep_kernel(
    const float* __restrict__ x, const float* __restrict__ nw,
    signed char* __restrict__ xq, float* __restrict__ srow,
    const float* __restrict__ wq, signed char* __restrict__ wb) {
  const int b = blockIdx.x;
  const int t = threadIdx.x;

  if (b < MROWS) {
    const float4* xr  = (const float4*)(x + (size_t)b * D_IN);
    const float4* nw4 = (const float4*)nw;

    float4 p[4];
    float ss = 0.f, mx = 0.f;
#pragma unroll
    for (int i = 0; i < 4; ++i) {
      const float4 v = xr[i * 256 + t];
      const float4 w = nw4[i * 256 + t];
      ss += v.x * v.x + v.y * v.y + v.z * v.z + v.w * v.w;
      p[i].x = v.x * w.x; p[i].y = v.y * w.y;
      p[i].z = v.z * w.z; p[i].w = v.w * w.w;
      mx = fmaxf(mx, fmaxf(fmaxf(fabsf(p[i].x), fabsf(p[i].y)),
                           fmaxf(fabsf(p[i].z), fabsf(p[i].w))));
    }
#pragma unroll
    for (int off = 32; off > 0; off >>= 1) {
      ss += __shfl_down(ss, off, 64);
      mx = fmaxf(mx, __shfl_down(mx, off, 64));
    }

    __shared__ float rs[4], rm[4];
    if ((t & 63) == 0) { rs[t >> 6] = ss; rm[t >> 6] = mx; }
    __syncthreads();
    const float scale =
        rsqrtf((rs[0] + rs[1] + rs[2] + rs[3]) * (1.0f / D_IN) + 1e-6f);
    const float rowmax = fmaxf(fmaxf(rm[0], rm[1]), fmaxf(rm[2], rm[3])) * scale;
    const float s   = fmaxf(rowmax, 1e-20f) * (1.0f / 127.0f);
    const float f   = scale / s;   // = scale * 127 / rowmax
    if (t == 0) srow[b] = s;

    int* out = (int*)(xq + (size_t)b * D_IN);
#pragma unroll
    for (int i = 0; i < 4; ++i) {
      const int q0 = (int)rintf(p[i].x * f);
      const int q1 = (int)rintf(p[i].y * f);
      const int q2 = (int)rintf(p[i].z * f);
      const int q3 = (int)rintf(p[i].w * f);
      out[i * 256 + t] =
          (q0 & 0xFF) | ((q1 & 0xFF) << 8) | ((q2 & 0xFF) << 16) | (q3 << 24);
    }
  } else {
    const int cb = b - MROWS;
    const float4* w4 = (const float4*)wq;
    int* o = (int*)wb;
#pragma unroll
    for (int i = 0; i < 4; ++i) {
      const int idx = cb * 1024 + i * 256 + t;
      const float4 v = w4[idx];
      const int q0 = (int)v.x, q1 = (int)v.y, q2 = (int)v.z, q3 = (int)v.w;
      o[idx] = (q0 & 0xFF) | ((q1 & 0xFF) << 8) | ((q2 & 0xFF) << 16) | (q3 << 24);
    }
  }
}

// ---------------- Kernel 2: i8 GEMM (A: MxK, B: NxK i.e. B^T) -------------
// mfma_i32_16x16x64_i8: per lane A[m=lane&15][k=(lane>>4)*16 + j], j in [0,16).
// C/D layout (shape-determined): col=lane&15, row=(lane>>4)*4+reg.
// LDS XOR-swizzle (proven 0 conflicts): 16B chunk (row, j) lives at slot
// j ^ ((row>>1)&3); applied by permuting the *global source* chunk,
// compensated in the ds_read address.
//
// R2 STRUCTURE: m201-style fine phase interleave. 256x256 tile, 8 waves
// (2Mx4N, wave 128x64). 3-slot LDS ring (3 x (16KB A + 16KB B) = 96 KB).
// Per K-tile, 2 phases:
//   P1: {ds_read A0-3,B0-3; stage A-half of tile T+2; BAR; prio1; 16 MFMA
//        (m0-3 x n0-3); prio0; BAR}
//   P2: {ds_read A4-7;      stage B-half of tile T+2; BAR; prio1; 16 MFMA
//        (m4-7); prio0; WVM(4); BAR}
// vmcnt(4) once per K-tile guarantees tile T+1 landed before its reads
// (tile T+2's 4 loads stay in flight across barriers — never drain to 0).
// Slot safety: slot (T+2)%3 was last read during tile T-1 and drained
// (compiler lgkm before that tile's MFMAs) >= 2 barriers before the stage.
#define BM 256
#define BN 256
#define BKB 64                  // K bytes per tile == one MFMA k-step
#define NKT (D_IN / BKB)        // 64 K-tiles
#define SLOT_BYTES (BM * BKB)   // 16 KB per ring slot per operand

#define WVM(n_) asm volatile("s_waitcnt vmcnt(" #n_ ")" ::: "memory")
#define BAR()   __builtin_amdgcn_s_barrier()

// Stage one operand half (2 x global_load_lds, 16B/lane) of tile at byte k0
// into ring slot ss.
#define STG_A(k0_, ss_)                                                       \
  do {                                                                        \
    _Pragma("unroll") for (int _i = 0; _i < 2; ++_i)                          \
        __builtin_amdgcn_global_load_lds(                                     \
            (__attribute__((address_space(1))) void*)(A + aOff[_i] + (k0_)),  \
            (__attribute__((address_space(3))) void*)&sA[ss_][ldsOff[_i]],    \
            16, 0, 0);                                                        \
  } while (0)
#define STG_B(k0_, ss_)                                                       \
  do {                                                                        \
    _Pragma("unroll") for (int _i = 0; _i < 2; ++_i)                          \
        __builtin_amdgcn_global_load_lds(                                     \
            (__attribute__((address_space(1))) void*)(B + bOff[_i] + (k0_)),  \
            (__attribute__((address_space(3))) void*)&sB[ss_][ldsOff[_i]],    \
            16, 0, 0);                                                        \
  } while (0)

#define READ_P1()                                                             \
  do {                                                                        \
    _Pragma("unroll") for (int _i = 0; _i < 4; ++_i)                          \
        af[_i] = *(const i32x4*)&sA[sC][aoff + _i * (16 * BKB)];              \
    _Pragma("unroll") for (int _j = 0; _j < 4; ++_j)                          \
        bf[_j] = *(const i32x4*)&sB[sC][boff + _j * (16 * BKB)];              \
  } while (0)
#define READ_P2()                                                             \
  do {                                                                        \
    _Pragma("unroll") for (int _i = 0; _i < 4; ++_i)                          \
        af[4 + _i] = *(const i32x4*)&sA[sC][aoff + (4 + _i) * (16 * BKB)];    \
  } while (0)

#define MFMA_HALF(base_)                                                      \
  do {                                                                        \
    __builtin_amdgcn_s_setprio(1);                                            \
    _Pragma("unroll") for (int _i = 0; _i < 4; ++_i)                          \
        _Pragma("unroll") for (int _j = 0; _j < 4; ++_j)                      \
            acc[(base_) + _i][_j] = __builtin_amdgcn_mfma_i32_16x16x64_i8(    \
                af[(base_) + _i], bf[_j], acc[(base_) + _i][_j], 0, 0, 0);    \
    __builtin_amdgcn_s_setprio(0);                                            \
  } while (0)

// One K-tile body. STGA_/STGB_ are the (possibly empty) stage statements;
// WAIT_ is the end-of-tile vmcnt statement (possibly empty).
#define TILE_BODY(STGA_, STGB_, WAIT_)                                        \
  do {                                                                        \
    i32x4 af[8], bf[4];                                                       \
    READ_P1();                                                                \
    STGA_;                                                                    \
    BAR();                                                                    \
    MFMA_HALF(0);                                                             \
    BAR();                                                                    \
    READ_P2();                                                                \
    STGB_;                                                                    \
    BAR();                                                                    \
    MFMA_HALF(4);                                                             \
    WAIT_;                                                                    \
    BAR();                                                                    \
    const int _t = sC; sC = sN; sN = sS; sS = _t;                             \
  } while (0)

__global__ __launch_bounds__(512, 2) void gemm_kernel(
    const signed char* __restrict__ A,   // MROWS x D_IN i8
    const signed char* __restrict__ B,   // D_OUT x D_IN i8
    const float* __restrict__ srow,      // MROWS   (per-row dequant scale)
    const float* __restrict__ gamma,     // D_OUT
    float* __restrict__ C) {             // MROWS x D_OUT fp32
  __shared__ __align__(16) signed char sA[3][SLOT_BYTES];  // 48 KB
  __shared__ __align__(16) signed char sB[3][SLOT_BYTES];  // 48 KB

  const int tid  = threadIdx.x;
  const int lane = tid & 63;
  const int wv   = tid >> 6;     // 0..7
  const int wm   = wv >> 2;      // 0..1: 128-row half of the 256-row tile
  const int wn   = wv & 3;       // 0..3: 64-col quarter of the 256-col tile
  const int bn   = blockIdx.x;   // 0..15
  const int bm   = blockIdx.y;   // 0..31

  i32x4 acc[8][4];
#pragma unroll
  for (int i = 0; i < 8; ++i)
#pragma unroll
    for (int j = 0; j < 4; ++j) acc[i][j] = (i32x4){0, 0, 0, 0};

  // Staging map: per tile per operand 1024 chunks of 16B; chunk
  // c = i*512 + tid -> tile row r = c>>2, swizzled k-byte offset.
  size_t aOff[2], bOff[2];
  int ldsOff[2];
#pragma unroll
  for (int i = 0; i < 2; ++i) {
    const int c  = i * 512 + tid;
    const int r  = c >> 2;
    const int cc = ((c & 3) ^ ((r >> 1) & 3)) * 16;
    aOff[i] = (size_t)(bm * BM + r) * D_IN + cc;
    bOff[i] = (size_t)(bn * BN + r) * D_IN + cc;
    ldsOff[i] = (i * 512 + wv * 64) * 16;  // wave-uniform base; +lane*16 by HW
  }

  // Fragment read offsets (swizzle-compensated; row base is a multiple of
  // 16 so (row>>1)&3 == (lane>>1)&3).
  const int kk   = (((lane >> 4) ^ ((lane >> 1) & 3))) * 16;
  const int aoff = (wm * 128 + (lane & 15)) * BKB + kk;
  const int boff = (wn * 64  + (lane & 15)) * BKB + kk;

  int sC = 0, sN = 1, sS = 2;

  // Prologue: stage tiles 0 and 1; wait for tile 0 (tile 1 stays in flight).
  STG_A(0, 0); STG_B(0, 0);
  STG_A(BKB, 1); STG_B(BKB, 1);
  WVM(4);
  BAR();

  // Main loop: tiles 0..NKT-3, each staging tile T+2 into slot sS.
#pragma unroll 1
  for (int T = 0; T < NKT - 2; ++T) {
    const int k2 = (T + 2) * BKB;
    TILE_BODY(STG_A(k2, sS), STG_B(k2, sS), WVM(4));
  }
  // Tail: tile NKT-2 (drain last tile's loads), then NKT-1.
  TILE_BODY(, , WVM(0));
  TILE_BODY(, , );

  // Epilogue: y = acc * srow[row] * gamma[col]
  const int col0 = bn * BN + wn * 64 + (lane & 15);
  const int row0 = bm * BM + wm * 128 + ((lane >> 4) * 4);
  float g[4];
#pragma unroll
  for (int j = 0; j < 4; ++j) g[j] = gamma[col0 + j * 16];

#pragma unroll
  for (int i = 0; i < 8; ++i) {
#pragma unroll
    for (int r = 0; r < 4; ++r) {
      const int row = row0 + i * 16 + r;
      const float sr = srow[row];
#pragma unroll
      for (int j = 0; j < 4; ++j) {
        C[(size_t)row * D_OUT + col0 + j * 16] =
            (float)acc[i][j][r] * sr * g[j];
      }
    }
  }
}

#undef TILE_BODY
#undef MFMA_HALF
#undef READ_P1
#undef READ_P2
#undef STG_A
#undef STG_B
#undef WVM
#undef BAR

extern "C" void kernel_launch(void* const* d_in, const int* in_sizes, int n_in,
                              void* d_out, int out_size, void* d_ws, size_t ws_size,
                              hipStream_t stream) {
  const float* x     = (const float*)d_in[0];  // (2,4096,4096)
  const float* nw    = (const float*)d_in[1];  // (4096,)
  const float* wq    = (const float*)d_in[2];  // (4096,4096) {-1,0,1}
  const float* gamma = (const float*)d_in[3];  // (4096,)
  float* y = (float*)d_out;

  // Workspace: xq i8 (32 MB) | wb i8 (16 MB) | srow fp32 (32 KB)
  signed char* xq = (signed char*)d_ws;
  signed char* wb = xq + (size_t)MROWS * D_IN;
  float* srow = (float*)(wb + (size_t)D_OUT * D_IN);

  prep_kernel<<<MROWS + 4096, 256, 0, stream>>>(x, nw, xq, srow, wq, wb);

  gemm_kernel<<<dim3(D_OUT / BN, MROWS / BM), 512, 0, stream>>>(xq, wb, srow, gamma, y);
}

// Round 3
// 399.791 us; speedup vs baseline: 1.0653x; 1.0653x over previous
//
#include <hip/hip_runtime.h>
#include <hip/hip_bf16.h>
#include <stdint.h>

#define D_IN  4096
#define D_OUT 4096
#define MROWS 8192   // 2 * 4096 rows of x

using i32x4 = __attribute__((ext_vector_type(4))) int;

// -------- Kernel 1 (fused): RMSNorm -> i8 xn (per-row absmax scale)
//          AND w_q fp32 -> i8 (exact, values in {-1,0,1}) ------------------
__global__ __launch_bounds__(256) void prep_kernel(
    const float* __restrict__ x, const float* __restrict__ nw,
    signed char* __restrict__ xq, float* __restrict__ srow,
    const float* __restrict__ wq, signed char* __restrict__ wb) {
  const int b = blockIdx.x;
  const int t = threadIdx.x;

  if (b < MROWS) {
    const float4* xr  = (const float4*)(x + (size_t)b * D_IN);
    const float4* nw4 = (const float4*)nw;

    float4 p[4];
    float ss = 0.f, mx = 0.f;
#pragma unroll
    for (int i = 0; i < 4; ++i) {
      const float4 v = xr[i * 256 + t];
      const float4 w = nw4[i * 256 + t];
      ss += v.x * v.x + v.y * v.y + v.z * v.z + v.w * v.w;
      p[i].x = v.x * w.x; p[i].y = v.y * w.y;
      p[i].z = v.z * w.z; p[i].w = v.w * w.w;
      mx = fmaxf(mx, fmaxf(fmaxf(fabsf(p[i].x), fabsf(p[i].y)),
                           fmaxf(fabsf(p[i].z), fabsf(p[i].w))));
    }
#pragma unroll
    for (int off = 32; off > 0; off >>= 1) {
      ss += __shfl_down(ss, off, 64);
      mx = fmaxf(mx, __shfl_down(mx, off, 64));
    }

    __shared__ float rs[4], rm[4];
    if ((t & 63) == 0) { rs[t >> 6] = ss; rm[t >> 6] = mx; }
    __syncthreads();
    const float scale =
        rsqrtf((rs[0] + rs[1] + rs[2] + rs[3]) * (1.0f / D_IN) + 1e-6f);
    const float rowmax = fmaxf(fmaxf(rm[0], rm[1]), fmaxf(rm[2], rm[3])) * scale;
    const float s   = fmaxf(rowmax, 1e-20f) * (1.0f / 127.0f);
    const float f   = scale / s;   // = scale * 127 / rowmax
    if (t == 0) srow[b] = s;

    int* out = (int*)(xq + (size_t)b * D_IN);
#pragma unroll
    for (int i = 0; i < 4; ++i) {
      const int q0 = (int)rintf(p[i].x * f);
      const int q1 = (int)rintf(p[i].y * f);
      const int q2 = (int)rintf(p[i].z * f);
      const int q3 = (int)rintf(p[i].w * f);
      out[i * 256 + t] =
          (q0 & 0xFF) | ((q1 & 0xFF) << 8) | ((q2 & 0xFF) << 16) | (q3 << 24);
    }
  } else {
    const int cb = b - MROWS;
    const float4* w4 = (const float4*)wq;
    int* o = (int*)wb;
#pragma unroll
    for (int i = 0; i < 4; ++i) {
      const int idx = cb * 1024 + i * 256 + t;
      const float4 v = w4[idx];
      const int q0 = (int)v.x, q1 = (int)v.y, q2 = (int)v.z, q3 = (int)v.w;
      o[idx] = (q0 & 0xFF) | ((q1 & 0xFF) << 8) | ((q2 & 0xFF) << 16) | (q3 << 24);
    }
  }
}

// ---------------- Kernel 2: i8 GEMM (A: MxK, B: NxK i.e. B^T) -------------
// mfma_i32_16x16x64_i8: per lane A[m=lane&15][k=(lane>>4)*16 + j], j in [0,16).
// C/D layout (shape-determined): col=lane&15, row=(lane>>4)*4+reg.
//
// R3 STRUCTURE (post-mortem of R2: barriers are the dominant schedule cost;
// give the compiler big unbroken bodies instead of more phases):
//   256x256 tile, 8 waves (2Mx4N, wave 128x64), BKB=128 (two MFMA k-steps
//   per staged tile), 2-deep LDS ring (2 x 32KB x {A,B} = 128 KB, 1 blk/CU).
//   ONE barrier per body (32 total; R1 had 64, R2 had 256). Within a body
//   the two k-steps have no barrier between them, so kk=1's ds_reads can
//   hide under kk=0's 32-MFMA cluster. End-of-body vmcnt(0) waits on the
//   stage issued ~2500 MFMA-cycles earlier -> effectively free.
//
// LDS swizzle for 128B rows (rows are bank-aligned: r*128 % 128 == 0, so a
// column read would be 16-way conflicted): 16B chunk j of row r lives at
// slot j ^ (r&7)  (involution over the 8 slots of the row). Applied by
// permuting the *global source* chunk (global_load_lds forces LDS slot =
// lane order), compensated in the ds_read address; for fragment reads the
// m-row base is a multiple of 16 so r&7 == lane&7. Bank audit: one wave's
// 64-lane ds_read_b128 hits each 16B bank-group exactly 8x = the 8-cycle
// floor for 1024B -> conflict-free.
#define BM 256
#define BN 256
#define BKB 128                 // K bytes per staged tile == 2 MFMA k-steps
#define NKT (D_IN / BKB)        // 32 staged tiles
#define SLOT_BYTES (BM * BKB)   // 32 KB per ring slot per operand

#define WVM(n_) asm volatile("s_waitcnt vmcnt(" #n_ ")" ::: "memory")
#define BAR()   __builtin_amdgcn_s_barrier()

// Stage one full tile (A+B, 4+4 global_load_lds, 16B/lane) at byte k0 into
// ring slot ss.
#define STAGE(k0_, ss_)                                                       \
  do {                                                                        \
    _Pragma("unroll") for (int _i = 0; _i < 4; ++_i)                          \
        __builtin_amdgcn_global_load_lds(                                     \
            (__attribute__((address_space(1))) void*)(A + aOff[_i] + (k0_)),  \
            (__attribute__((address_space(3))) void*)&sA[ss_][ldsOff[_i]],    \
            16, 0, 0);                                                        \
    _Pragma("unroll") for (int _i = 0; _i < 4; ++_i)                          \
        __builtin_amdgcn_global_load_lds(                                     \
            (__attribute__((address_space(1))) void*)(B + bOff[_i] + (k0_)),  \
            (__attribute__((address_space(3))) void*)&sB[ss_][ldsOff[_i]],    \
            16, 0, 0);                                                        \
  } while (0)

// One MFMA k-step (kk_ in {0,1}) out of ring slot s_.
#define COMPUTE_K(s_, kk_)                                                    \
  do {                                                                        \
    i32x4 af[8], bf[4];                                                       \
    const int _ks = (((kk_)*4 + kx) ^ sx) * 16;                               \
    _Pragma("unroll") for (int _i = 0; _i < 8; ++_i)                          \
        af[_i] = *(const i32x4*)&sA[s_][aoff0 + _i * (16 * BKB) + _ks];       \
    _Pragma("unroll") for (int _j = 0; _j < 4; ++_j)                          \
        bf[_j] = *(const i32x4*)&sB[s_][boff0 + _j * (16 * BKB) + _ks];       \
    __builtin_amdgcn_s_setprio(1);                                            \
    _Pragma("unroll") for (int _i = 0; _i < 8; ++_i)                          \
        _Pragma("unroll") for (int _j = 0; _j < 4; ++_j)                      \
            acc[_i][_j] = __builtin_amdgcn_mfma_i32_16x16x64_i8(              \
                af[_i], bf[_j], acc[_i][_j], 0, 0, 0);                        \
    __builtin_amdgcn_s_setprio(0);                                            \
  } while (0)

__global__ __launch_bounds__(512, 2) void gemm_kernel(
    const signed char* __restrict__ A,   // MROWS x D_IN i8
    const signed char* __restrict__ B,   // D_OUT x D_IN i8
    const float* __restrict__ srow,      // MROWS   (per-row dequant scale)
    const float* __restrict__ gamma,     // D_OUT
    float* __restrict__ C) {             // MROWS x D_OUT fp32
  __shared__ __align__(16) signed char sA[2][SLOT_BYTES];  // 64 KB
  __shared__ __align__(16) signed char sB[2][SLOT_BYTES];  // 64 KB

  const int tid  = threadIdx.x;
  const int lane = tid & 63;
  const int wv   = tid >> 6;     // 0..7
  const int wm   = wv >> 2;      // 0..1: 128-row half of the 256-row tile
  const int wn   = wv & 3;       // 0..3: 64-col quarter of the 256-col tile
  const int bn   = blockIdx.x;   // 0..15
  const int bm   = blockIdx.y;   // 0..31

  i32x4 acc[8][4];
#pragma unroll
  for (int i = 0; i < 8; ++i)
#pragma unroll
    for (int j = 0; j < 4; ++j) acc[i][j] = (i32x4){0, 0, 0, 0};

  // Staging map: per tile per operand 2048 chunks of 16B; chunk
  // c = i*512 + tid -> tile row r = c>>3, row-slot j = c&7, global source
  // chunk j ^ (r&7) (swizzle pre-applied on the source address).
  size_t aOff[4], bOff[4];
  int ldsOff[4];
#pragma unroll
  for (int i = 0; i < 4; ++i) {
    const int c  = i * 512 + tid;
    const int r  = c >> 3;
    const int j  = c & 7;
    const int cc = ((j ^ (r & 7)) * 16);
    aOff[i] = (size_t)(bm * BM + r) * D_IN + cc;
    bOff[i] = (size_t)(bn * BN + r) * D_IN + cc;
    ldsOff[i] = (i * 512 + wv * 64) * 16;  // wave-uniform base; +lane*16 by HW
  }

  // Fragment read bases (swizzle compensated inside COMPUTE_K via kx/sx;
  // m-row base is a multiple of 16 so r&7 == lane&7).
  const int kx = lane >> 4;      // k-chunk within the 64B k-step
  const int sx = lane & 7;       // swizzle XOR key
  const int aoff0 = (wm * 128 + (lane & 15)) * BKB;
  const int boff0 = (wn * 64  + (lane & 15)) * BKB;

  // Prologue: stage tile 0 into slot 0 and wait for it.
  STAGE(0, 0);
  WVM(0);
  BAR();

  // Main loop: body T computes staged tile T (slot T&1, k-steps 2T, 2T+1)
  // and stages tile T+1 into slot (T+1)&1 (whose readers drained before the
  // barrier that ended body T-1).
#pragma unroll 1
  for (int T = 0; T < NKT - 1; ++T) {
    const int s = T & 1;
    STAGE((T + 1) * BKB, s ^ 1);
    COMPUTE_K(s, 0);
    COMPUTE_K(s, 1);
    WVM(0);
    BAR();
  }
  // Last tile: no stage, no wait.
  COMPUTE_K((NKT - 1) & 1, 0);
  COMPUTE_K((NKT - 1) & 1, 1);

  // Epilogue: y = acc * srow[row] * gamma[col]
  const int col0 = bn * BN + wn * 64 + (lane & 15);
  const int row0 = bm * BM + wm * 128 + ((lane >> 4) * 4);
  float g[4];
#pragma unroll
  for (int j = 0; j < 4; ++j) g[j] = gamma[col0 + j * 16];

#pragma unroll
  for (int i = 0; i < 8; ++i) {
#pragma unroll
    for (int r = 0; r < 4; ++r) {
      const int row = row0 + i * 16 + r;
      const float sr = srow[row];
#pragma unroll
      for (int j = 0; j < 4; ++j) {
        C[(size_t)row * D_OUT + col0 + j * 16] =
            (float)acc[i][j][r] * sr * g[j];
      }
    }
  }
}

#undef STAGE
#undef COMPUTE_K
#undef WVM
#undef BAR

extern "C" void kernel_launch(void* const* d_in, const int* in_sizes, int n_in,
                              void* d_out, int out_size, void* d_ws, size_t ws_size,
                              hipStream_t stream) {
  const float* x     = (const float*)d_in[0];  // (2,4096,4096)
  const float* nw    = (const float*)d_in[1];  // (4096,)
  const float* wq    = (const float*)d_in[2];  // (4096,4096) {-1,0,1}
  const float* gamma = (const float*)d_in[3];  // (4096,)
  float* y = (float*)d_out;

  // Workspace: xq i8 (32 MB) | wb i8 (16 MB) | srow fp32 (32 KB)
  signed char* xq = (signed char*)d_ws;
  signed char* wb = xq + (size_t)MROWS * D_IN;
  float* srow = (float*)(wb + (size_t)D_OUT * D_IN);

  prep_kernel<<<MROWS + 4096, 256, 0, stream>>>(x, nw, xq, srow, wq, wb);

  gemm_kernel<<<dim3(D_OUT / BN, MROWS / BM), 512, 0, stream>>>(xq, wb, srow, gamma, y);
}